// Round 7
// baseline (184.343 us; speedup 1.0000x reference)
//
#include <hip/hip_runtime.h>

// Problem constants
#define DD 64
#define LL 50
#define NB 4096
#define NT 100

typedef __attribute__((ext_vector_type(8))) __bf16 bf16x8;
typedef __attribute__((ext_vector_type(4))) float f32x4;

__device__ __forceinline__ float sigmoidf_(float x) {
    return 1.0f / (1.0f + __expf(-x));
}
__device__ __forceinline__ float b2f(unsigned short h) {
    union { unsigned int u; float f; } v; v.u = ((unsigned int)h) << 16; return v.f;
}
// round-half-up f32->bf16, pack two into one u32 (hi -> upper 16)
__device__ __forceinline__ unsigned pack_bf16(float hi, float lo) {
    union { float f; unsigned u; } a, b;
    a.f = hi; b.f = lo;
    return ((a.u + 0x8000u) & 0xffff0000u) | ((b.u + 0x8000u) >> 16);
}
__device__ __forceinline__ uint4 cvt8u(const float* f) {
    uint4 r;
    r.x = pack_bf16(f[1], f[0]);
    r.y = pack_bf16(f[3], f[2]);
    r.z = pack_bf16(f[5], f[4]);
    r.w = pack_bf16(f[7], f[6]);
    return r;
}
__device__ __forceinline__ bf16x8 cvt8(const float* f) {
    return __builtin_bit_cast(bf16x8, cvt8u(f));
}

// ===========================================================================
// K0: batched user GEMM. A = U[16 users x 64], B = [Wu^T (n<64) | igu (n=64+l)].
// One wave per 16 users; grid 256. ufg gets both biases folded.
// ===========================================================================
__global__ __launch_bounds__(64) void k0_user(
    const int* __restrict__ uid_g, const float* __restrict__ user_table,
    const float* __restrict__ Wu, const float* __restrict__ bu,
    const float* __restrict__ bi, const float* __restrict__ igu,
    float* __restrict__ ufg_ws, float* __restrict__ t2_ws)
{
    const int lane = threadIdx.x;
    const int c = lane & 15, q = lane >> 4;
    const int uid = uid_g[blockIdx.x * 16 + c];
    const float* urow = user_table + (size_t)uid * DD;

    bf16x8 af[2];
#pragma unroll
    for (int kf = 0; kf < 2; kf++) {
        float tmp[8];
        *(float4*)&tmp[0] = *(const float4*)(urow + kf * 32 + q * 8);
        *(float4*)&tmp[4] = *(const float4*)(urow + kf * 32 + q * 8 + 4);
        af[kf] = cvt8(tmp);
    }

#pragma unroll
    for (int ni = 0; ni < 8; ni++) {
        f32x4 a = {0.f, 0.f, 0.f, 0.f};
#pragma unroll
        for (int kf = 0; kf < 2; kf++) {
            const int k0 = kf * 32 + q * 8;
            float tmp[8];
            if (ni < 4) {
                const float* src = Wu + (ni * 16 + c) * DD + k0;
                *(float4*)&tmp[0] = *(const float4*)src;
                *(float4*)&tmp[4] = *(const float4*)(src + 4);
            } else {
                const int l = ni * 16 + c - 64;
#pragma unroll
                for (int j = 0; j < 8; j++)
                    tmp[j] = (l < LL) ? igu[(k0 + j) * LL + l] : 0.f;
            }
            a = __builtin_amdgcn_mfma_f32_16x16x32_bf16(af[kf], cvt8(tmp), a, 0, 0, 0);
        }
        const int n = ni * 16 + c;
#pragma unroll
        for (int reg = 0; reg < 4; reg++) {
            const int bo = blockIdx.x * 16 + q * 4 + reg;
            if (n < DD)           ufg_ws[bo * DD + n] = a[reg] + bu[n] + bi[n];
            else if (n < DD + LL) t2_ws[bo * DD + (n - DD)] = a[reg];
        }
    }
}

// ===========================================================================
// K1 (fused union + score): one WAVE per b, 4 b per block, NO barriers.
// All LDS wave-private. After v is computed, the same wave streams its b's
// 100 W2 rows — overlapping the item-gather/MFMA of other blocks with the
// W2 gather of this one.
// ===========================================================================
__global__ __launch_bounds__(256) void k1_fused(
    const int* __restrict__ uid_g, const int* __restrict__ iid_g,
    const int* __restrict__ tgt_g,
    const float* __restrict__ user_table, const float* __restrict__ item_table,
    const float* __restrict__ W2, const float* __restrict__ b2,
    const float* __restrict__ Wi, const float* __restrict__ igi,
    const float* __restrict__ ufg_ws, const float* __restrict__ t2_ws,
    float* __restrict__ out)
{
    const int tid = threadIdx.x;
    const int w = tid >> 6, lane = tid & 63;
    const int c = lane & 15, q = lane >> 4;
    const int b = blockIdx.x * 4 + w;

    __shared__ unsigned short sE[4][LL][72];   // bf16 item slab (28.8 KB)
    __shared__ float sT[4][DD];                // t2
    __shared__ int   sids[4][NT];              // target ids
    __shared__ float sv4[4][DD];               // final v
    __shared__ float sout[4][NT];              // scores

    // ---- target ids -> LDS (independent of everything; issue first) ----
    const int* tb = tgt_g + b * NT;
    sids[w][lane] = tb[lane];
    if (lane < NT - 64) sids[w][64 + lane] = tb[64 + lane];

    // ---- t2 stage (coalesced) ----
    sT[w][lane] = t2_ws[b * DD + lane];

    // ---- item gather -> A-frags + LDS slab (wave-private) ----
    const int* iid = iid_g + b * LL;
    bf16x8 ea[4][2];
#pragma unroll
    for (int mi = 0; mi < 4; mi++) {
        const int l = mi * 16 + c;
        if (l < LL) {
            const float* src = item_table + (size_t)iid[l] * DD;
#pragma unroll
            for (int kf = 0; kf < 2; kf++) {
                float tmp[8];
                *(float4*)&tmp[0] = *(const float4*)(src + kf * 32 + q * 8);
                *(float4*)&tmp[4] = *(const float4*)(src + kf * 32 + q * 8 + 4);
                uint4 p = cvt8u(tmp);
                ea[mi][kf] = __builtin_bit_cast(bf16x8, p);
                *(uint4*)&sE[w][l][kf * 32 + q * 8] = p;
            }
        } else {
            uint4 z = {0u, 0u, 0u, 0u};
            ea[mi][0] = __builtin_bit_cast(bf16x8, z);
            ea[mi][1] = __builtin_bit_cast(bf16x8, z);
        }
    }

    // ---- Wi frags direct from global (L2-hot 16 KB table) ----
    bf16x8 wb[4][2];
#pragma unroll
    for (int ni = 0; ni < 4; ni++)
#pragma unroll
        for (int kf = 0; kf < 2; kf++) {
            float tmp[8];
            const float* src = Wi + (ni * 16 + c) * DD + kf * 32 + q * 8;
            *(float4*)&tmp[0] = *(const float4*)src;
            *(float4*)&tmp[4] = *(const float4*)(src + 4);
            wb[ni][kf] = cvt8(tmp);
        }

    float ufg4[4], igi4[4];
#pragma unroll
    for (int ni = 0; ni < 4; ni++) {
        ufg4[ni] = ufg_ws[b * DD + ni * 16 + c];
        igi4[ni] = igi[ni * 16 + c];
    }

    // ---- MFMA + epilogue ----
    float unum[4] = {0.f, 0.f, 0.f, 0.f};
    float sip[4]  = {0.f, 0.f, 0.f, 0.f};
    float isum = 0.f;

#pragma unroll
    for (int mi = 0; mi < 4; mi++) {
        f32x4 acc[4];
#pragma unroll
        for (int ni = 0; ni < 4; ni++) {
            f32x4 a = {0.f, 0.f, 0.f, 0.f};
            a = __builtin_amdgcn_mfma_f32_16x16x32_bf16(ea[mi][0], wb[ni][0], a, 0, 0, 0);
            a = __builtin_amdgcn_mfma_f32_16x16x32_bf16(ea[mi][1], wb[ni][1], a, 0, 0, 0);
            acc[ni] = a;
        }
        float gated[4][4], inst_r[4];
#pragma unroll
        for (int reg = 0; reg < 4; reg++) {
            const int l = mi * 16 + q * 4 + reg;
            const int valid = (l < LL);
            const int lc = valid ? l : 0;
            const float lm = valid ? 1.f : 0.f;
            float t1 = 0.f;
#pragma unroll
            for (int ni = 0; ni < 4; ni++) {
                const float e = b2f(sE[w][lc][ni * 16 + c]) * lm;
                const float g = sigmoidf_(acc[ni][reg] + ufg4[ni]);
                const float gd = e * g;
                gated[reg][ni] = gd;
                t1 += gd * igi4[ni];
                sip[ni] += e;
            }
            t1 += __shfl_xor(t1, 1); t1 += __shfl_xor(t1, 2);
            t1 += __shfl_xor(t1, 4); t1 += __shfl_xor(t1, 8);
            inst_r[reg] = valid ? sigmoidf_(t1 + sT[w][lc]) : 0.f;
        }
#pragma unroll
        for (int reg = 0; reg < 4; reg++) {
            isum += inst_r[reg];
#pragma unroll
            for (int ni = 0; ni < 4; ni++)
                unum[ni] += gated[reg][ni] * inst_r[reg];
        }
    }

#pragma unroll
    for (int ni = 0; ni < 4; ni++) {
        unum[ni] += __shfl_xor(unum[ni], 16); unum[ni] += __shfl_xor(unum[ni], 32);
        sip[ni]  += __shfl_xor(sip[ni], 16);  sip[ni]  += __shfl_xor(sip[ni], 32);
    }
    isum += __shfl_xor(isum, 16); isum += __shfl_xor(isum, 32);

    const float un = (q == 0) ? unum[0] : (q == 1) ? unum[1] : (q == 2) ? unum[2] : unum[3];
    const float si = (q == 0) ? sip[0]  : (q == 1) ? sip[1]  : (q == 2) ? sip[2]  : sip[3];
    const int uid = uid_g[b];
    const float u = user_table[(size_t)uid * DD + lane];
    sv4[w][lane] = u + un / isum + si;   // wave-private; lgkmcnt ordering suffices

    // ---- score phase: 16 lanes per row, 25 rounds of 4 rows ----
    const int j = lane & 15, g2 = lane >> 4;
    float4 vr = *(const float4*)&sv4[w][j * 4];

#pragma unroll 5
    for (int i = 0; i < 25; i++) {
        const int t = i * 4 + g2;
        const int id = sids[w][t];
        float4 wv = *(const float4*)(W2 + (size_t)id * DD + j * 4);
        float s = wv.x * vr.x + wv.y * vr.y + wv.z * vr.z + wv.w * vr.w;
        s += __shfl_xor(s, 1);
        s += __shfl_xor(s, 2);
        s += __shfl_xor(s, 4);
        s += __shfl_xor(s, 8);
        if (j == 0) sout[w][t] = s + b2[id];
    }

    // coalesced final stores (wave-synchronous LDS: in-order, no barrier)
    out[b * NT + lane] = sout[w][lane];
    if (lane < NT - 64) out[b * NT + 64 + lane] = sout[w][64 + lane];
}

// ===========================================================================
extern "C" void kernel_launch(void* const* d_in, const int* in_sizes, int n_in,
                              void* d_out, int out_size, void* d_ws, size_t ws_size,
                              hipStream_t stream)
{
    const int* user_ids        = (const int*)d_in[0];
    const int* item_seq_ids    = (const int*)d_in[1];
    const int* target_item_ids = (const int*)d_in[2];
    const float* user_tab      = (const float*)d_in[3];
    const float* item_tab      = (const float*)d_in[4];
    const float* W2_tab        = (const float*)d_in[5];
    const float* b2_tab        = (const float*)d_in[6];
    const float* fg_item_W     = (const float*)d_in[7];
    const float* fg_item_b     = (const float*)d_in[8];
    const float* fg_user_W     = (const float*)d_in[9];
    const float* fg_user_b     = (const float*)d_in[10];
    const float* igi           = (const float*)d_in[11];
    const float* igu           = (const float*)d_in[12];
    float* out = (float*)d_out;

    float* ufg_ws = (float*)d_ws;              // [4096][64]
    float* t2_ws  = ufg_ws + NB * DD;          // [4096][64] (cols 0..49 used)

    k0_user<<<NB / 16, 64, 0, stream>>>(user_ids, user_tab, fg_user_W,
                                        fg_user_b, fg_item_b, igu, ufg_ws, t2_ws);
    k1_fused<<<NB / 4, 256, 0, stream>>>(user_ids, item_seq_ids, target_item_ids,
                                         user_tab, item_tab, W2_tab, b2_tab,
                                         fg_item_W, igi, ufg_ws, t2_ws, out);
}

// Round 8
// 170.236 us; speedup vs baseline: 1.0829x; 1.0829x over previous
//
#include <hip/hip_runtime.h>

// Problem constants
#define DD 64
#define LL 50
#define NB 4096
#define NT 100

typedef __attribute__((ext_vector_type(8))) __bf16 bf16x8;
typedef __attribute__((ext_vector_type(4))) float f32x4;

__device__ __forceinline__ float sigmoidf_(float x) {
    return 1.0f / (1.0f + __expf(-x));
}
__device__ __forceinline__ float b2f(unsigned short h) {
    union { unsigned int u; float f; } v; v.u = ((unsigned int)h) << 16; return v.f;
}
// round-half-up f32->bf16, pack two into one u32 (hi -> upper 16)
__device__ __forceinline__ unsigned pack_bf16(float hi, float lo) {
    union { float f; unsigned u; } a, b;
    a.f = hi; b.f = lo;
    return ((a.u + 0x8000u) & 0xffff0000u) | ((b.u + 0x8000u) >> 16);
}
__device__ __forceinline__ uint4 cvt8u(const float* f) {
    uint4 r;
    r.x = pack_bf16(f[1], f[0]);
    r.y = pack_bf16(f[3], f[2]);
    r.z = pack_bf16(f[5], f[4]);
    r.w = pack_bf16(f[7], f[6]);
    return r;
}
__device__ __forceinline__ bf16x8 cvt8(const float* f) {
    return __builtin_bit_cast(bf16x8, cvt8u(f));
}

// ===========================================================================
// K0: batched user GEMM. A = U[16 users x 64], B = [Wu^T (n<64) | igu (n=64+l)].
// One wave per 16 users; grid 256. ufg gets both biases folded.
// ===========================================================================
__global__ __launch_bounds__(64) void k0_user(
    const int* __restrict__ uid_g, const float* __restrict__ user_table,
    const float* __restrict__ Wu, const float* __restrict__ bu,
    const float* __restrict__ bi, const float* __restrict__ igu,
    float* __restrict__ ufg_ws, float* __restrict__ t2_ws)
{
    const int lane = threadIdx.x;
    const int c = lane & 15, q = lane >> 4;
    const int uid = uid_g[blockIdx.x * 16 + c];
    const float* urow = user_table + (size_t)uid * DD;

    bf16x8 af[2];
#pragma unroll
    for (int kf = 0; kf < 2; kf++) {
        float tmp[8];
        *(float4*)&tmp[0] = *(const float4*)(urow + kf * 32 + q * 8);
        *(float4*)&tmp[4] = *(const float4*)(urow + kf * 32 + q * 8 + 4);
        af[kf] = cvt8(tmp);
    }

#pragma unroll
    for (int ni = 0; ni < 8; ni++) {
        f32x4 a = {0.f, 0.f, 0.f, 0.f};
#pragma unroll
        for (int kf = 0; kf < 2; kf++) {
            const int k0 = kf * 32 + q * 8;
            float tmp[8];
            if (ni < 4) {
                const float* src = Wu + (ni * 16 + c) * DD + k0;
                *(float4*)&tmp[0] = *(const float4*)src;
                *(float4*)&tmp[4] = *(const float4*)(src + 4);
            } else {
                const int l = ni * 16 + c - 64;
#pragma unroll
                for (int j = 0; j < 8; j++)
                    tmp[j] = (l < LL) ? igu[(k0 + j) * LL + l] : 0.f;
            }
            a = __builtin_amdgcn_mfma_f32_16x16x32_bf16(af[kf], cvt8(tmp), a, 0, 0, 0);
        }
        const int n = ni * 16 + c;
#pragma unroll
        for (int reg = 0; reg < 4; reg++) {
            const int bo = blockIdx.x * 16 + q * 4 + reg;
            if (n < DD)           ufg_ws[bo * DD + n] = a[reg] + bu[n] + bi[n];
            else if (n < DD + LL) t2_ws[bo * DD + (n - DD)] = a[reg];
        }
    }
}

// ===========================================================================
// K1: union vector, TWO waves per b (2 b per 256-thread block).
// Wave h ∈ {0,1} of pair p owns rows l = 32h .. 32h+31 (h=1: 18 valid):
// gathers them, computes its 2 m-tiles (8 MFMAs), epilogue partials;
// one barrier combines unum/sip/isum across the pair.
// LDS ~21 KB -> 7 blocks/CU -> 28 waves/CU.
// ===========================================================================
__global__ __launch_bounds__(256) void k1_union(
    const int* __restrict__ uid_g, const int* __restrict__ iid_g,
    const float* __restrict__ user_table, const float* __restrict__ item_table,
    const float* __restrict__ Wi, const float* __restrict__ igi,
    const float* __restrict__ ufg_ws, const float* __restrict__ t2_ws,
    float* __restrict__ v_ws)
{
    const int tid = threadIdx.x;
    const int w = tid >> 6, lane = tid & 63;
    const int p = w >> 1, h = w & 1;          // pair, half
    const int c = lane & 15, q = lane >> 4;
    const int b = blockIdx.x * 2 + p;

    __shared__ unsigned short sE[4][32][72];  // per-wave slab: its 32 rows (18.4 KB)
    __shared__ float sT[2][DD];               // t2 per pair
    __shared__ float sU[4][DD];               // per-wave unum (d-indexed)
    __shared__ float sS[4][DD];               // per-wave sip
    __shared__ float sI[4];                   // per-wave isum

    // t2 stage (h=0 wave of each pair, coalesced)
    if (h == 0) sT[p][lane] = t2_ws[b * DD + lane];

    // ---- item gather: rows l = 32h + r, r = mi'*16 + c ----
    const int* iid = iid_g + b * LL;
    bf16x8 ea[2][2];
#pragma unroll
    for (int mi = 0; mi < 2; mi++) {
        const int r = mi * 16 + c;
        const int l = 32 * h + r;
        if (l < LL) {
            const float* src = item_table + (size_t)iid[l] * DD;
#pragma unroll
            for (int kf = 0; kf < 2; kf++) {
                float tmp[8];
                *(float4*)&tmp[0] = *(const float4*)(src + kf * 32 + q * 8);
                *(float4*)&tmp[4] = *(const float4*)(src + kf * 32 + q * 8 + 4);
                uint4 pk = cvt8u(tmp);
                ea[mi][kf] = __builtin_bit_cast(bf16x8, pk);
                *(uint4*)&sE[w][r][kf * 32 + q * 8] = pk;
            }
        } else {
            uint4 z = {0u, 0u, 0u, 0u};
            ea[mi][0] = __builtin_bit_cast(bf16x8, z);
            ea[mi][1] = __builtin_bit_cast(bf16x8, z);
        }
    }

    // ---- Wi frags direct from global (16 KB, L2-hot) ----
    bf16x8 wb[4][2];
#pragma unroll
    for (int ni = 0; ni < 4; ni++)
#pragma unroll
        for (int kf = 0; kf < 2; kf++) {
            float tmp[8];
            const float* src = Wi + (ni * 16 + c) * DD + kf * 32 + q * 8;
            *(float4*)&tmp[0] = *(const float4*)src;
            *(float4*)&tmp[4] = *(const float4*)(src + 4);
            wb[ni][kf] = cvt8(tmp);
        }

    float ufg4[4], igi4[4];
#pragma unroll
    for (int ni = 0; ni < 4; ni++) {
        ufg4[ni] = ufg_ws[b * DD + ni * 16 + c];
        igi4[ni] = igi[ni * 16 + c];
    }

    float unum[4] = {0.f, 0.f, 0.f, 0.f};
    float sip[4]  = {0.f, 0.f, 0.f, 0.f};
    float isum = 0.f;

    // need sT before epilogue (written by the other wave of the pair)
    __syncthreads();

#pragma unroll
    for (int mi = 0; mi < 2; mi++) {
        f32x4 acc[4];
#pragma unroll
        for (int ni = 0; ni < 4; ni++) {
            f32x4 a = {0.f, 0.f, 0.f, 0.f};
            a = __builtin_amdgcn_mfma_f32_16x16x32_bf16(ea[mi][0], wb[ni][0], a, 0, 0, 0);
            a = __builtin_amdgcn_mfma_f32_16x16x32_bf16(ea[mi][1], wb[ni][1], a, 0, 0, 0);
            acc[ni] = a;
        }
        float gated[4][4], inst_r[4];
#pragma unroll
        for (int reg = 0; reg < 4; reg++) {
            const int r = mi * 16 + q * 4 + reg;
            const int l = 32 * h + r;
            const int valid = (l < LL);
            const float lm = valid ? 1.f : 0.f;
            const int rc = valid ? r : 0;
            float t1 = 0.f;
#pragma unroll
            for (int ni = 0; ni < 4; ni++) {
                const float e = b2f(sE[w][rc][ni * 16 + c]) * lm;
                const float g = sigmoidf_(acc[ni][reg] + ufg4[ni]);
                const float gd = e * g;
                gated[reg][ni] = gd;
                t1 += gd * igi4[ni];
                sip[ni] += e;
            }
            t1 += __shfl_xor(t1, 1); t1 += __shfl_xor(t1, 2);
            t1 += __shfl_xor(t1, 4); t1 += __shfl_xor(t1, 8);
            inst_r[reg] = valid ? sigmoidf_(t1 + sT[p][32 * h + rc]) : 0.f;
        }
#pragma unroll
        for (int reg = 0; reg < 4; reg++) {
            isum += inst_r[reg];
#pragma unroll
            for (int ni = 0; ni < 4; ni++)
                unum[ni] += gated[reg][ni] * inst_r[reg];
        }
    }

#pragma unroll
    for (int ni = 0; ni < 4; ni++) {
        unum[ni] += __shfl_xor(unum[ni], 16); unum[ni] += __shfl_xor(unum[ni], 32);
        sip[ni]  += __shfl_xor(sip[ni], 16);  sip[ni]  += __shfl_xor(sip[ni], 32);
    }
    isum += __shfl_xor(isum, 16); isum += __shfl_xor(isum, 32);

    // lane's d = lane = 16q + c -> take partial ni == q
    const float un = (q == 0) ? unum[0] : (q == 1) ? unum[1] : (q == 2) ? unum[2] : unum[3];
    const float si = (q == 0) ? sip[0]  : (q == 1) ? sip[1]  : (q == 2) ? sip[2]  : sip[3];
    sU[w][lane] = un;
    sS[w][lane] = si;
    if (lane == 0) sI[w] = isum;
    __syncthreads();

    if (h == 0) {
        const int d = lane;
        const float num = sU[2 * p][d] + sU[2 * p + 1][d];
        const float ss  = sS[2 * p][d] + sS[2 * p + 1][d];
        const float den = sI[2 * p] + sI[2 * p + 1];
        const int uid = uid_g[b];
        const float u = user_table[(size_t)uid * DD + d];
        v_ws[b * DD + d] = u + num / den + ss;
    }
}

// ===========================================================================
// K2: streaming scores. One block per b; 16 lanes per (b,t), one float4/lane.
// ===========================================================================
__global__ __launch_bounds__(256) void k2_score(
    const int* __restrict__ tgt_g, const float* __restrict__ W2,
    const float* __restrict__ b2, const float* __restrict__ v_ws,
    float* __restrict__ out)
{
    const int b = blockIdx.x;
    const int tid = threadIdx.x;
    __shared__ float sv[DD];
    __shared__ int sids[NT];
    __shared__ float sout[NT + 12];

    if (tid < DD) sv[tid] = v_ws[b * DD + tid];
    if (tid < NT) sids[tid] = tgt_g[b * NT + tid];
    __syncthreads();

    const int j = tid & 15, g = tid >> 4;
    float4 vr = *(const float4*)&sv[j * 4];

#pragma unroll
    for (int it = 0; it < 7; it++) {
        const int t = it * 16 + g;
        if (t < NT) {
            const int id = sids[t];
            float4 wv = *(const float4*)(W2 + (size_t)id * DD + j * 4);
            float s = wv.x * vr.x + wv.y * vr.y + wv.z * vr.z + wv.w * vr.w;
            s += __shfl_xor(s, 1);
            s += __shfl_xor(s, 2);
            s += __shfl_xor(s, 4);
            s += __shfl_xor(s, 8);
            if (j == 0) sout[t] = s + b2[id];
        }
    }
    __syncthreads();
    if (tid < NT) out[b * NT + tid] = sout[tid];
}

// ===========================================================================
extern "C" void kernel_launch(void* const* d_in, const int* in_sizes, int n_in,
                              void* d_out, int out_size, void* d_ws, size_t ws_size,
                              hipStream_t stream)
{
    const int* user_ids        = (const int*)d_in[0];
    const int* item_seq_ids    = (const int*)d_in[1];
    const int* target_item_ids = (const int*)d_in[2];
    const float* user_tab      = (const float*)d_in[3];
    const float* item_tab      = (const float*)d_in[4];
    const float* W2_tab        = (const float*)d_in[5];
    const float* b2_tab        = (const float*)d_in[6];
    const float* fg_item_W     = (const float*)d_in[7];
    const float* fg_item_b     = (const float*)d_in[8];
    const float* fg_user_W     = (const float*)d_in[9];
    const float* fg_user_b     = (const float*)d_in[10];
    const float* igi           = (const float*)d_in[11];
    const float* igu           = (const float*)d_in[12];
    float* out = (float*)d_out;

    float* ufg_ws = (float*)d_ws;              // [4096][64]
    float* t2_ws  = ufg_ws + NB * DD;          // [4096][64] (cols 0..49 used)
    float* v_ws   = t2_ws + NB * DD;           // [4096][64]

    k0_user<<<NB / 16, 64, 0, stream>>>(user_ids, user_tab, fg_user_W,
                                        fg_user_b, fg_item_b, igu, ufg_ws, t2_ws);
    k1_union<<<NB / 2, 256, 0, stream>>>(user_ids, item_seq_ids, user_tab,
                                         item_tab, fg_item_W, igi, ufg_ws,
                                         t2_ws, v_ws);
    k2_score<<<NB, 256, 0, stream>>>(target_item_ids, W2_tab, b2_tab, v_ws, out);
}

// Round 9
// 159.390 us; speedup vs baseline: 1.1566x; 1.0680x over previous
//
#include <hip/hip_runtime.h>

// Problem constants
#define DD 64
#define LL 50
#define NB 4096
#define NT 100

typedef __attribute__((ext_vector_type(8))) __bf16 bf16x8;
typedef __attribute__((ext_vector_type(4))) float f32x4;

__device__ __forceinline__ float sigmoidf_(float x) {
    return 1.0f / (1.0f + __expf(-x));
}
// round-half-up f32->bf16, pack two into one u32 (hi -> upper 16)
__device__ __forceinline__ unsigned pack_bf16(float hi, float lo) {
    union { float f; unsigned u; } a, b;
    a.f = hi; b.f = lo;
    return ((a.u + 0x8000u) & 0xffff0000u) | ((b.u + 0x8000u) >> 16);
}
__device__ __forceinline__ uint4 cvt8u(const float* f) {
    uint4 r;
    r.x = pack_bf16(f[1], f[0]);
    r.y = pack_bf16(f[3], f[2]);
    r.z = pack_bf16(f[5], f[4]);
    r.w = pack_bf16(f[7], f[6]);
    return r;
}
__device__ __forceinline__ bf16x8 cvt8(const float* f) {
    return __builtin_bit_cast(bf16x8, cvt8u(f));
}
// async global->LDS: wave-uniform LDS base + lane*size (gfx950)
__device__ __forceinline__ void glds16(const float* g, float* l) {
    __builtin_amdgcn_global_load_lds(
        (const __attribute__((address_space(1))) void*)g,
        (__attribute__((address_space(3))) void*)l, 16, 0, 0);
}
__device__ __forceinline__ void glds4(const float* g, float* l) {
    __builtin_amdgcn_global_load_lds(
        (const __attribute__((address_space(1))) void*)g,
        (__attribute__((address_space(3))) void*)l, 4, 0, 0);
}

// ===========================================================================
// K0: blocks 0..255: batched user GEMM (16 users/wave).
//     block 256: pack fg_item_W -> bf16 row-major (k1 reads frags directly).
// ===========================================================================
__global__ __launch_bounds__(64) void k0_user(
    const int* __restrict__ uid_g, const float* __restrict__ user_table,
    const float* __restrict__ Wu, const float* __restrict__ bu,
    const float* __restrict__ bi, const float* __restrict__ igu,
    const float* __restrict__ Wi,
    float* __restrict__ ufg_ws, float* __restrict__ t2_ws,
    unsigned short* __restrict__ wiB_ws)
{
    if (blockIdx.x == 256) {   // Wi -> bf16 pack
        const int n = threadIdx.x;
        float tmp[64];
#pragma unroll
        for (int c4 = 0; c4 < 16; c4++)
            *(float4*)&tmp[c4 * 4] = *(const float4*)(Wi + n * DD + c4 * 4);
#pragma unroll
        for (int ch = 0; ch < 8; ch++)
            *(uint4*)(wiB_ws + n * DD + ch * 8) = cvt8u(tmp + ch * 8);
        return;
    }

    const int lane = threadIdx.x;
    const int c = lane & 15, q = lane >> 4;
    const int uid = uid_g[blockIdx.x * 16 + c];
    const float* urow = user_table + (size_t)uid * DD;

    bf16x8 af[2];
#pragma unroll
    for (int kf = 0; kf < 2; kf++) {
        float tmp[8];
        *(float4*)&tmp[0] = *(const float4*)(urow + kf * 32 + q * 8);
        *(float4*)&tmp[4] = *(const float4*)(urow + kf * 32 + q * 8 + 4);
        af[kf] = cvt8(tmp);
    }

#pragma unroll
    for (int ni = 0; ni < 8; ni++) {
        f32x4 a = {0.f, 0.f, 0.f, 0.f};
#pragma unroll
        for (int kf = 0; kf < 2; kf++) {
            const int k0 = kf * 32 + q * 8;
            float tmp[8];
            if (ni < 4) {
                const float* src = Wu + (ni * 16 + c) * DD + k0;
                *(float4*)&tmp[0] = *(const float4*)src;
                *(float4*)&tmp[4] = *(const float4*)(src + 4);
            } else {
                const int l = ni * 16 + c - 64;
#pragma unroll
                for (int j = 0; j < 8; j++)
                    tmp[j] = (l < LL) ? igu[(k0 + j) * LL + l] : 0.f;
            }
            a = __builtin_amdgcn_mfma_f32_16x16x32_bf16(af[kf], cvt8(tmp), a, 0, 0, 0);
        }
        const int n = ni * 16 + c;
#pragma unroll
        for (int reg = 0; reg < 4; reg++) {
            const int bo = blockIdx.x * 16 + q * 4 + reg;
            if (n < DD)           ufg_ws[bo * DD + n] = a[reg] + bu[n] + bi[n];
            else if (n < DD + LL) t2_ws[bo * DD + (n - DD)] = a[reg];
        }
    }
}

// ===========================================================================
// K1: one WAVE per b, 64-thread blocks, grid 4096.
// Item rows staged f32 into LDS via 13 async global_load_lds_dwordx4
// (fire-and-forget -> 13 outstanding misses/wave). 16B chunks XOR-swizzled
// by (row&7) on the global side so LDS frag reads are conflict-free.
// ===========================================================================
__global__ __launch_bounds__(64) void k1_union(
    const int* __restrict__ uid_g, const int* __restrict__ iid_g,
    const float* __restrict__ user_table, const float* __restrict__ item_table,
    const unsigned short* __restrict__ wiB, const float* __restrict__ igi,
    const float* __restrict__ ufg_ws, const float* __restrict__ t2_ws,
    float* __restrict__ v_ws)
{
    const int lane = threadIdx.x;
    const int c = lane & 15, q = lane >> 4;
    const int b = blockIdx.x;

    __shared__ __align__(16) float sE[52 * DD + DD];   // 52 rows + t2 slot
    float* sT = sE + 52 * DD;

    // ---- ids for this lane's gather rows (13 independent loads) ----
    const int* iidp = iid_g + b * LL;
    int ids[13];
#pragma unroll
    for (int s = 0; s < 13; s++) {
        const int r = 4 * s + (lane >> 4);
        ids[s] = iidp[r < LL ? r : LL - 1];
    }

    // ---- async item gather: instr s covers rows 4s..4s+3 (256 B each) ----
    // lane i -> row r = 4s + i/16, phys chunk p = i%16 holds logical chunk
    // j = p ^ (r&7)  (XOR swizzle for bank-conflict-free readback)
#pragma unroll
    for (int s = 0; s < 13; s++) {
        const int r = 4 * s + (lane >> 4);
        const int j = (lane & 15) ^ (r & 7);
        glds16(item_table + (size_t)ids[s] * DD + j * 4, sE + s * 256);
    }
    // t2 (f32, lane-contiguous)
    glds4(t2_ws + b * DD + (lane < LL ? lane : LL - 1), sT);

    // ---- independent register loads (overlap the gather) ----
    bf16x8 wb[4][2];
#pragma unroll
    for (int ni = 0; ni < 4; ni++)
#pragma unroll
        for (int kf = 0; kf < 2; kf++)
            wb[ni][kf] = __builtin_bit_cast(bf16x8,
                *(const uint4*)(wiB + (ni * 16 + c) * DD + kf * 32 + q * 8));

    float ufg4[4], igi4[4];
#pragma unroll
    for (int ni = 0; ni < 4; ni++) {
        ufg4[ni] = ufg_ws[b * DD + ni * 16 + c];
        igi4[ni] = igi[ni * 16 + c];
    }
    const int uid = uid_g[b];
    const float u = user_table[(size_t)uid * DD + lane];

    __syncthreads();   // drains vmcnt (glds complete), 1-wave barrier ~free

    // ---- A-frags from LDS (deswizzled), invalid rows zeroed ----
    bf16x8 ea[4][2];
#pragma unroll
    for (int mi = 0; mi < 4; mi++) {
        const int row = mi * 16 + c;
        const int rr = (row < LL) ? row : 0;
        const float* rowp = sE + rr * DD;
        const int s7 = rr & 7;
#pragma unroll
        for (int kf = 0; kf < 2; kf++) {
            float tmp[8];
            const int ch0 = (kf * 8 + 2 * q) ^ s7;
            const int ch1 = (kf * 8 + 2 * q + 1) ^ s7;
            *(float4*)&tmp[0] = *(const float4*)(rowp + ch0 * 4);
            *(float4*)&tmp[4] = *(const float4*)(rowp + ch1 * 4);
            if (row >= LL) {
#pragma unroll
                for (int i = 0; i < 8; i++) tmp[i] = 0.f;
            }
            ea[mi][kf] = cvt8(tmp);
        }
    }

    // ---- MFMA + epilogue ----
    float unum[4] = {0.f, 0.f, 0.f, 0.f};
    float sip[4]  = {0.f, 0.f, 0.f, 0.f};
    float isum = 0.f;

#pragma unroll
    for (int mi = 0; mi < 4; mi++) {
        f32x4 acc[4];
#pragma unroll
        for (int ni = 0; ni < 4; ni++) {
            f32x4 a = {0.f, 0.f, 0.f, 0.f};
            a = __builtin_amdgcn_mfma_f32_16x16x32_bf16(ea[mi][0], wb[ni][0], a, 0, 0, 0);
            a = __builtin_amdgcn_mfma_f32_16x16x32_bf16(ea[mi][1], wb[ni][1], a, 0, 0, 0);
            acc[ni] = a;
        }
        float gated[4][4], inst_r[4];
#pragma unroll
        for (int reg = 0; reg < 4; reg++) {
            const int l = mi * 16 + q * 4 + reg;
            const int valid = (l < LL);
            const int lr = valid ? l : 0;
            const int s7 = lr & 7;
            float t1 = 0.f;
#pragma unroll
            for (int ni = 0; ni < 4; ni++) {
                const int phys = (4 * ni + (c >> 2)) ^ s7;
                const float ev = sE[lr * DD + phys * 4 + (c & 3)];
                const float e = valid ? ev : 0.f;
                const float g = sigmoidf_(acc[ni][reg] + ufg4[ni]);
                const float gd = e * g;
                gated[reg][ni] = gd;
                t1 += gd * igi4[ni];
                sip[ni] += e;
            }
            t1 += __shfl_xor(t1, 1); t1 += __shfl_xor(t1, 2);
            t1 += __shfl_xor(t1, 4); t1 += __shfl_xor(t1, 8);
            inst_r[reg] = valid ? sigmoidf_(t1 + sT[lr]) : 0.f;
        }
#pragma unroll
        for (int reg = 0; reg < 4; reg++) {
            isum += inst_r[reg];
#pragma unroll
            for (int ni = 0; ni < 4; ni++)
                unum[ni] += gated[reg][ni] * inst_r[reg];
        }
    }

#pragma unroll
    for (int ni = 0; ni < 4; ni++) {
        unum[ni] += __shfl_xor(unum[ni], 16); unum[ni] += __shfl_xor(unum[ni], 32);
        sip[ni]  += __shfl_xor(sip[ni], 16);  sip[ni]  += __shfl_xor(sip[ni], 32);
    }
    isum += __shfl_xor(isum, 16); isum += __shfl_xor(isum, 32);

    // lane's d = lane = 16q + c -> take partial ni == q
    const float un = (q == 0) ? unum[0] : (q == 1) ? unum[1] : (q == 2) ? unum[2] : unum[3];
    const float si = (q == 0) ? sip[0]  : (q == 1) ? sip[1]  : (q == 2) ? sip[2]  : sip[3];
    v_ws[b * DD + lane] = u + un / isum + si;
}

// ===========================================================================
// K2: streaming scores, MLP-batched. One block per b; 16 lanes per (b,t).
// All 7 W2 row loads + 7 b2 loads issued before any reduction.
// ===========================================================================
__global__ __launch_bounds__(256) void k2_score(
    const int* __restrict__ tgt_g, const float* __restrict__ W2,
    const float* __restrict__ b2, const float* __restrict__ v_ws,
    float* __restrict__ out)
{
    const int b = blockIdx.x;
    const int tid = threadIdx.x;
    __shared__ float sv[DD];
    __shared__ int sids[112];
    __shared__ float sout[112];

    if (tid < DD) sv[tid] = v_ws[b * DD + tid];
    if (tid < 112) {
        const int t = (tid < NT) ? tid : NT - 1;
        sids[tid] = tgt_g[b * NT + t];
    }
    __syncthreads();

    const int j = tid & 15, g = tid >> 4;
    float4 vr = *(const float4*)&sv[j * 4];

    int id[7];
#pragma unroll
    for (int i = 0; i < 7; i++) id[i] = sids[i * 16 + g];
    float4 wv[7];
#pragma unroll
    for (int i = 0; i < 7; i++)
        wv[i] = *(const float4*)(W2 + (size_t)id[i] * DD + j * 4);
    float bb[7];
#pragma unroll
    for (int i = 0; i < 7; i++) bb[i] = b2[id[i]];

#pragma unroll
    for (int i = 0; i < 7; i++) {
        float s = wv[i].x * vr.x + wv[i].y * vr.y + wv[i].z * vr.z + wv[i].w * vr.w;
        s += __shfl_xor(s, 1); s += __shfl_xor(s, 2);
        s += __shfl_xor(s, 4); s += __shfl_xor(s, 8);
        if (j == 0) sout[i * 16 + g] = s + bb[i];
    }
    __syncthreads();
    if (tid < NT) out[b * NT + tid] = sout[tid];
}

// ===========================================================================
extern "C" void kernel_launch(void* const* d_in, const int* in_sizes, int n_in,
                              void* d_out, int out_size, void* d_ws, size_t ws_size,
                              hipStream_t stream)
{
    const int* user_ids        = (const int*)d_in[0];
    const int* item_seq_ids    = (const int*)d_in[1];
    const int* target_item_ids = (const int*)d_in[2];
    const float* user_tab      = (const float*)d_in[3];
    const float* item_tab      = (const float*)d_in[4];
    const float* W2_tab        = (const float*)d_in[5];
    const float* b2_tab        = (const float*)d_in[6];
    const float* fg_item_W     = (const float*)d_in[7];
    const float* fg_item_b     = (const float*)d_in[8];
    const float* fg_user_W     = (const float*)d_in[9];
    const float* fg_user_b     = (const float*)d_in[10];
    const float* igi           = (const float*)d_in[11];
    const float* igu           = (const float*)d_in[12];
    float* out = (float*)d_out;

    float* ufg_ws = (float*)d_ws;                       // [4096][64] f32
    float* t2_ws  = ufg_ws + NB * DD;                   // [4096][64] f32
    float* v_ws   = t2_ws + NB * DD;                    // [4096][64] f32
    unsigned short* wiB_ws = (unsigned short*)(v_ws + NB * DD);  // [64][64] bf16

    k0_user<<<257, 64, 0, stream>>>(user_ids, user_tab, fg_user_W, fg_user_b,
                                    fg_item_b, igu, fg_item_W,
                                    ufg_ws, t2_ws, wiB_ws);
    k1_union<<<NB, 64, 0, stream>>>(user_ids, item_seq_ids, user_tab, item_tab,
                                    wiB_ws, igi, ufg_ws, t2_ws, v_ws);
    k2_score<<<NB, 256, 0, stream>>>(target_item_ids, W2_tab, b2_tab, v_ws, out);
}